// Round 12
// baseline (181.016 us; speedup 1.0000x reference)
//
#include <hip/hip_runtime.h>

// SSIM3D, (4,1,128,128,128) fp32, separable 11-tap Gaussian, scalar mean out.
//
// R18: X-MAJOR FLOAT4 FIELD LAYOUT [n][z][y][x][f]. R17 post-mortem: -20%
// writes AND -22% VALU moved A only -2us -> not write-bound, not VALU-bound;
// remaining fixed cost = per-step memory-op issue+latency at ~5 waves/CU
// (occupancy pinned ~17% all session). Attack instruction COUNT:
//   A stores: 4 scalar dwords -> 1 dwordx4/output (coalesced 1KB/wave).
//   B loads:  4 scalar dwords (stride 512B) -> 1 dwordx4/step.
// Bytes unchanged (WRITE_SIZE == 131072 KB invariant). Everything else
// byte-identical to R17 (absmax 0.0 x6): A write-2-ahead ring, y-chunk 16,
// (128,2); B depth-6 named-register pipeline, batches reversed.
// Decision rule: A still ~70us + occupancy ~17% -> structural floor of the
// 2-kernel shape -> fused single-kernel next round.

#define SLICE (128*128)        // 16384
#define S  (128*SLICE)         // 2097152 per field per batch
#define FROW 512               // floats per y-row   (128 x * 4 fields)
#define FSL  65536             // floats per z-slice (128 y * FROW)
#define C1_ 0.0001f
#define C2_ 0.0009f

__device__ __forceinline__ void make_g_s(float* gs) {
    float g[11]; float s = 0.f;
#pragma unroll
    for (int i = 0; i < 11; ++i) {
        float d = (float)(i - 5);
        g[i] = __expf(-d * d / 4.5f);
        s += g[i];
    }
    float inv = 1.f / s;
#pragma unroll
    for (int i = 0; i < 11; ++i)
        gs[i] = __int_as_float(__builtin_amdgcn_readfirstlane(
                    __float_as_int(g[i] * inv)));
}

// ---------------- Kernel A: x-conv + y-conv, walk y ----------------
// grid: 4n * 128z * 8yc = 4096 blocks of 128 threads (2 independent waves).
// Thread owns x = tid; walks 16 y outputs (26 input rows, fully unrolled).
// Per-wave LDS ring: 4 slots x (img1 row | img2 row), rows padded to 160
// floats (data at dwords [8..135], zeros outside): maskless 11-tap.
// Pipeline: global load row(t+4) at t; LDS-write row(t+2) at t; read slot
// t&3 (written t-2). Fields per output: float4{conv a, conv b,
// conv(a^2+b^2), conv ab} stored as ONE dwordx4.
#define RB    160              // dwords per padded row
#define RSLOT (2*RB)           // 320 dwords per ring slot
#define WRING (4*RSLOT)        // 1280 dwords per wave ring (4 slots) = 5 KiB

#define STEPA(T_, TM_, J0_, J1_, STORE_, OKC_) do {                           \
    const int T__ = (T_);                                                     \
    int sp__ = T__ + 4; if (sp__ > 25) sp__ = 25;                             \
    int rowc__ = min(max(y0 + sp__ - 5, 0), 127);                             \
    float4 Rn__ = *(const float4*)(src + (size_t)rowc__ * 128);               \
    if (OKC_) {                                                               \
        const float* rp__ = p_rd + ((T_) & 3) * RSLOT;                        \
        float u1__ = 0.f, u2__ = 0.f, ss__ = 0.f, a12__ = 0.f;                \
        _Pragma("unroll")                                                     \
        for (int j = 0; j < 6; ++j) {                                         \
            float2 va__ = *(const float2*)(rp__ + 2 * j);                     \
            float2 vb__ = *(const float2*)(rp__ + RB + 2 * j);                \
            {                                                                 \
                float wj__ = w12[2 * j];                                      \
                float ta__ = wj__ * va__.x, tb__ = wj__ * vb__.x;             \
                u1__ += ta__; u2__ += tb__;                                   \
                ss__  = fmaf(ta__, va__.x, ss__);                             \
                ss__  = fmaf(tb__, vb__.x, ss__);                             \
                a12__ = fmaf(ta__, vb__.x, a12__);                            \
            }                                                                 \
            {                                                                 \
                float wj__ = w12[2 * j + 1];                                  \
                float ta__ = wj__ * va__.y, tb__ = wj__ * vb__.y;             \
                u1__ += ta__; u2__ += tb__;                                   \
                ss__  = fmaf(ta__, va__.y, ss__);                             \
                ss__  = fmaf(tb__, vb__.y, ss__);                             \
                a12__ = fmaf(ta__, vb__.y, a12__);                            \
            }                                                                 \
        }                                                                     \
        _Pragma("unroll")                                                     \
        for (int j = (J0_); j <= (J1_); ++j) {                                \
            const int sl__ = ((TM_) + j + 1) % 11;                            \
            float wy__ = gs[10 - j];                                          \
            acc[0][sl__] = fmaf(wy__, u1__,  acc[0][sl__]);                   \
            acc[1][sl__] = fmaf(wy__, u2__,  acc[1][sl__]);                   \
            acc[2][sl__] = fmaf(wy__, ss__,  acc[2][sl__]);                   \
            acc[3][sl__] = fmaf(wy__, a12__, acc[3][sl__]);                   \
        }                                                                     \
    }                                                                         \
    *(float4*)(p_wr + (((T_) + 2) & 3) * RSLOT) = h1;  /* row T+2 */          \
    if (STORE_) {                                                             \
        const int es__ = ((TM_) + 1) % 11;                                    \
        float4 v__;                                                           \
        v__.x = acc[0][es__]; v__.y = acc[1][es__];                           \
        v__.z = acc[2][es__]; v__.w = acc[3][es__];                           \
        *(float4*)(fb + (size_t)(y0 + T__ - 10) * FROW) = v__;                \
        acc[0][es__] = 0.f; acc[1][es__] = 0.f;                               \
        acc[2][es__] = 0.f; acc[3][es__] = 0.f;                               \
    }                                                                         \
    h1 = h2; h2 = Rn__;                                                       \
} while (0)

__global__ __launch_bounds__(128, 2)
void ssimA(const float* __restrict__ img1, const float* __restrict__ img2,
           float* __restrict__ fields) {
    __shared__ __align__(16) float ring[2 * WRING];   // 10 KiB (2 waves)
    float gs[11]; make_g_s(gs);
    const int x = threadIdx.x;                 // 0..127 (output column)
    const int w = x >> 6, l = x & 63;          // wave, lane
    const int b = blockIdx.x;
    const int yc = b & 7, z = (b >> 3) & 127, n = b >> 10;
    const int y0 = yc * 16;
    // lanes 0-31 stage the img1 row (float4 each), lanes 32-63 the img2 row
    const float* src = (l < 32 ? img1 : img2)
                     + (size_t)n * S + (size_t)z * SLICE + 4 * (l & 31);
    float* fb = fields + (size_t)(n * 128 + z) * FSL + 4 * x;

    // per-parity 12-tap weights over the aligned window [e, e+11],
    // e = (x-5)&~1, p = (x-5)&1; tap k has weight g[k-p] (0 outside 0..10).
    const int p = (x - 5) & 1;
    const int e = (x - 5) - p;                 // even, in [-6, 122]
    float w12[12];
#pragma unroll
    for (int k = 0; k < 12; ++k) {
        float we = (k <= 10) ? gs[k] : 0.f;            // p == 0
        float wo = (k >= 1) ? gs[k - 1] : 0.f;         // p == 1
        w12[k] = p ? wo : we;
    }

    float* wring = ring + w * WRING;           // private per-wave ring
    float* p_rd = wring + (8 + e);             // aligned window base (8B)
    float* p_wr = wring + ((l < 32) ? 0 : RB) + 8 + 4 * (l & 31);

    // zero whole ring once: pads stay zero forever (x-boundary = free)
    for (int i = l; i < WRING; i += 64) wring[i] = 0.f;

    float acc[4][11];
#pragma unroll
    for (int f = 0; f < 4; ++f)
#pragma unroll
        for (int s2 = 0; s2 < 11; ++s2) acc[f][s2] = 0.f;

    // prologue: slots 0,1 <- rows for steps 0,1; h1,h2 <- rows for steps 2,3
    float4 h1, h2;
    {
        int r0 = min(max(y0 - 5, 0), 127);
        int r1 = min(max(y0 - 4, 0), 127);
        int r2 = min(max(y0 - 3, 0), 127);
        int r3 = min(max(y0 - 2, 0), 127);
        float4 R0 = *(const float4*)(src + (size_t)r0 * 128);
        float4 R1 = *(const float4*)(src + (size_t)r1 * 128);
        h1        = *(const float4*)(src + (size_t)r2 * 128);
        h2        = *(const float4*)(src + (size_t)r3 * 128);
        *(float4*)(p_wr)         = R0;         // slot 0
        *(float4*)(p_wr + RSLOT) = R1;         // slot 1
    }

    // head: t = 0..9 (partial y-window, row may be < 0; no stores)
#pragma unroll
    for (int t = 0; t < 10; ++t)
        STEPA(t, t, 10 - t, 10, false, (y0 + t - 5 >= 0));
    // mid: t = 10..15 -- full window, store every step
#pragma unroll
    for (int t = 10; t < 16; ++t)
        STEPA(t, t % 11, 0, 10, true, true);
    // drain: t = 16..25 (tail taps; row may be > 127 only at yc=7; store)
#pragma unroll
    for (int t = 16; t < 26; ++t)
        STEPA(t, t % 11, 0, 25 - t, true, (y0 + t - 5 < 128));
}

// ---------------- Kernel B: z-conv + map + reduce, walk z ----------------
// grid: 4n * 128y * 4zc = 2048 blocks of 128 threads (2 waves, 1 y-row).
// Thread owns x = tid; walks 32 z outputs. Batches reversed (freshest A
// output first -> L3 hits). Depth-6 float4 pipeline (P0_..P5_, named regs);
// x-major layout: ONE dwordx4 load per step (was 4 scalar strided dwords).
#define STEPB(T_, TM_, J0_, J1_, STORE_, OKC_) do {                           \
    const int T__ = (T_);                                                     \
    int sp__ = T__ + 6; if (sp__ > 41) sp__ = 41;                             \
    size_t off__ = (size_t)min(max(z0 + sp__ - 5, 0), 127) * FSL;             \
    float4 N__ = *(const float4*)(base + off__);                              \
    if (OKC_) {                                                               \
        _Pragma("unroll")                                                     \
        for (int j = (J0_); j <= (J1_); ++j) {                                \
            const int sl__ = ((TM_) + j + 1) % 11;                            \
            float wz__ = gs[10 - j];                                          \
            acc[0][sl__] = fmaf(wz__, P0_.x, acc[0][sl__]);                   \
            acc[1][sl__] = fmaf(wz__, P0_.y, acc[1][sl__]);                   \
            acc[2][sl__] = fmaf(wz__, P0_.z, acc[2][sl__]);                   \
            acc[3][sl__] = fmaf(wz__, P0_.w, acc[3][sl__]);                   \
        }                                                                     \
    }                                                                         \
    if (STORE_) {                                                             \
        const int es__ = ((TM_) + 1) % 11;                                    \
        float m1__ = acc[0][es__], m2__ = acc[1][es__];                       \
        float ps__ = acc[2][es__], p12__ = acc[3][es__];                      \
        float m1s__ = m1__ * m1__, m2s__ = m2__ * m2__, m12__ = m1__ * m2__;  \
        float v12__ = ps__ - m1s__ - m2s__;     /* sigma1^2 + sigma2^2 */     \
        float cv__  = p12__ - m12__;            /* sigma12 */                 \
        float num__ = (2.f * m12__ + C1_) * (2.f * cv__ + C2_);               \
        float den__ = (m1s__ + m2s__ + C1_) * (v12__ + C2_);                  \
        sum += num__ / den__;                                                 \
        _Pragma("unroll")                                                     \
        for (int f = 0; f < 4; ++f) acc[f][es__] = 0.f;                       \
    }                                                                         \
    P0_ = P1_; P1_ = P2_; P2_ = P3_; P3_ = P4_; P4_ = P5_; P5_ = N__;         \
} while (0)

__global__ __launch_bounds__(128, 2)
void ssimB(const float* __restrict__ fields, float* __restrict__ partials) {
    float gs[11]; make_g_s(gs);
    const int tid = threadIdx.x;
    const int x = tid;                          // 0..127
    const int b = blockIdx.x;
    const int zc = b & 3, y = (b >> 2) & 127;
    const int n = 3 - (b >> 9);                 // reverse batches (L3 hits)
    const int z0 = zc * 32;
    const float* base = fields + (size_t)n * 128 * FSL
                      + (size_t)y * FROW + 4 * x;

    float acc[4][11];
#pragma unroll
    for (int f = 0; f < 4; ++f)
#pragma unroll
        for (int s2 = 0; s2 < 11; ++s2) acc[f][s2] = 0.f;

    float sum = 0.f;

    // depth-6 prologue: slices for steps 0..5 (z0-5 .. z0)
    float4 P0_, P1_, P2_, P3_, P4_, P5_;
    {
        P0_ = *(const float4*)(base + (size_t)min(max(z0 - 5, 0), 127) * FSL);
        P1_ = *(const float4*)(base + (size_t)min(max(z0 - 4, 0), 127) * FSL);
        P2_ = *(const float4*)(base + (size_t)min(max(z0 - 3, 0), 127) * FSL);
        P3_ = *(const float4*)(base + (size_t)min(max(z0 - 2, 0), 127) * FSL);
        P4_ = *(const float4*)(base + (size_t)min(max(z0 - 1, 0), 127) * FSL);
        P5_ = *(const float4*)(base + (size_t)min(max(z0 - 0, 0), 127) * FSL);
    }

    // head: t = 0..9
#pragma unroll
    for (int t = 0; t < 10; ++t)
        STEPB(t, t, 10 - t, 10, false, (z0 + t - 5 >= 0));
    // steady: t = 10..31 -- branch-free
#pragma unroll 1
    for (int blk = 0; blk < 2; ++blk) {
#pragma unroll
        for (int tt = 0; tt < 11; ++tt)
            STEPB(10 + blk * 11 + tt, (10 + tt) % 11, 0, 10, true, true);
    }
    // drain: t = 32..41
#pragma unroll
    for (int t = 32; t < 42; ++t)
        STEPB(t, t % 11, 0, 41 - t, true, (z0 + t - 5 < 128));

    // 2-wave reduce
#pragma unroll
    for (int o = 32; o > 0; o >>= 1) sum += __shfl_down(sum, o, 64);
    __shared__ float ws2[2];
    if ((tid & 63) == 0) ws2[tid >> 6] = sum;
    __syncthreads();
    if (tid == 0) partials[blockIdx.x] = ws2[0] + ws2[1];
}

// ---------------- final reduce ----------------
__global__ void ssim_final(const float* __restrict__ partial, int n,
                           float* __restrict__ out, double inv_count) {
    int tid = threadIdx.x;
    double s = 0.0;
    for (int i = tid; i < n; i += 256) s += (double)partial[i];
#pragma unroll
    for (int o = 32; o > 0; o >>= 1) s += __shfl_down(s, o, 64);
    __shared__ double wsum[4];
    int lane = tid & 63, wid = tid >> 6;
    if (lane == 0) wsum[wid] = s;
    __syncthreads();
    if (tid == 0)
        out[0] = (float)((wsum[0] + wsum[1] + wsum[2] + wsum[3]) * inv_count);
}

extern "C" void kernel_launch(void* const* d_in, const int* in_sizes, int n_in,
                              void* d_out, int out_size, void* d_ws, size_t ws_size,
                              hipStream_t stream) {
    const float* img1 = (const float*)d_in[0];
    const float* img2 = (const float*)d_in[1];
    float* out = (float*)d_out;

    float* fields   = (float*)d_ws;                    // 16*S floats (134 MB)
    float* partials = fields + 16 * (size_t)S;         // 2048 floats

    ssimA<<<4096, 128, 0, stream>>>(img1, img2, fields);
    ssimB<<<2048, 128, 0, stream>>>(fields, partials);
    ssim_final<<<1, 256, 0, stream>>>(partials, 2048, out,
                                      1.0 / ((double)S * 4));
}

// Round 14
// 178.730 us; speedup vs baseline: 1.0128x; 1.0128x over previous
//
#include <hip/hip_runtime.h>

// SSIM3D, (4,1,128,128,128) fp32, separable 11-tap Gaussian, scalar mean out.
//
// R20 == R19 resubmit (R19 hit "container failed twice" -- no verdict; same
// infra signature as R7/R15, both of which passed verbatim on resubmit.
// Audit: float2 stores 8/16B-aligned, max index = 16*S-1 exactly, float4
// loads 16B-aligned, static-indexed pipeline -- no crash mechanism).
//
// R19: BEST-OF-EACH consolidation.
// R18 post-mortem: float4-store packing spilled A (WRITE 143360 = 131072 +
// 12288 spill, VGPR=128cap) -> A 78us. Totals ledger isolates B (invisible
// in top-5): total-A was 93us with R13's (256,1)x1024 4-wave B, 103-108us
// with all (128,2)x2048 2-wave variants -> B's best shape is 256-thr blocks.
// This round:
//  A: R17's proven 71us structure on x-major [n][z][y][x][f] layout with
//     2x float2 stores (pair-aligned tuples, no quad RA constraint).
//  B: R13's block shape (256,1) grid 1024 + R18's single dwordx4 load/step
//     + depth-6 named-register pipeline; batches reversed.
// Invariants: A WRITE_SIZE == 131072 KB, VGPR < 128.
// Decision rule: total >= 175us -> B-shape theory wrong -> fuse or declare
// ~170 structural plateau.

#define SLICE (128*128)        // 16384
#define S  (128*SLICE)         // 2097152 per field per batch
#define FROW 512               // floats per y-row   (128 x * 4 fields)
#define FSL  65536             // floats per z-slice (128 y * FROW)
#define C1_ 0.0001f
#define C2_ 0.0009f

__device__ __forceinline__ void make_g_s(float* gs) {
    float g[11]; float s = 0.f;
#pragma unroll
    for (int i = 0; i < 11; ++i) {
        float d = (float)(i - 5);
        g[i] = __expf(-d * d / 4.5f);
        s += g[i];
    }
    float inv = 1.f / s;
#pragma unroll
    for (int i = 0; i < 11; ++i)
        gs[i] = __int_as_float(__builtin_amdgcn_readfirstlane(
                    __float_as_int(g[i] * inv)));
}

// ---------------- Kernel A: x-conv + y-conv, walk y ----------------
// grid: 4n * 128z * 8yc = 4096 blocks of 128 threads (2 independent waves).
// Thread owns x = tid; walks 16 y outputs (26 input rows, fully unrolled).
// Per-wave LDS ring: 4 slots x (img1 row | img2 row), rows padded to 160
// floats (data at dwords [8..135], zeros outside): maskless 11-tap.
// Pipeline: global load row(t+4) at t; LDS-write row(t+2) at t; read slot
// t&3 (written t-2). Output per point: {conv a, conv b, conv(a^2+b^2),
// conv ab} x-major, two float2 stores.
#define RB    160              // dwords per padded row
#define RSLOT (2*RB)           // 320 dwords per ring slot
#define WRING (4*RSLOT)        // 1280 dwords per wave ring (4 slots) = 5 KiB

#define STEPA(T_, TM_, J0_, J1_, STORE_, OKC_) do {                           \
    const int T__ = (T_);                                                     \
    int sp__ = T__ + 4; if (sp__ > 25) sp__ = 25;                             \
    int rowc__ = min(max(y0 + sp__ - 5, 0), 127);                             \
    float4 Rn__ = *(const float4*)(src + (size_t)rowc__ * 128);               \
    if (OKC_) {                                                               \
        const float* rp__ = p_rd + ((T_) & 3) * RSLOT;                        \
        float u1__ = 0.f, u2__ = 0.f, ss__ = 0.f, a12__ = 0.f;                \
        _Pragma("unroll")                                                     \
        for (int j = 0; j < 6; ++j) {                                         \
            float2 va__ = *(const float2*)(rp__ + 2 * j);                     \
            float2 vb__ = *(const float2*)(rp__ + RB + 2 * j);                \
            {                                                                 \
                float wj__ = w12[2 * j];                                      \
                float ta__ = wj__ * va__.x, tb__ = wj__ * vb__.x;             \
                u1__ += ta__; u2__ += tb__;                                   \
                ss__  = fmaf(ta__, va__.x, ss__);                             \
                ss__  = fmaf(tb__, vb__.x, ss__);                             \
                a12__ = fmaf(ta__, vb__.x, a12__);                            \
            }                                                                 \
            {                                                                 \
                float wj__ = w12[2 * j + 1];                                  \
                float ta__ = wj__ * va__.y, tb__ = wj__ * vb__.y;             \
                u1__ += ta__; u2__ += tb__;                                   \
                ss__  = fmaf(ta__, va__.y, ss__);                             \
                ss__  = fmaf(tb__, vb__.y, ss__);                             \
                a12__ = fmaf(ta__, vb__.y, a12__);                            \
            }                                                                 \
        }                                                                     \
        _Pragma("unroll")                                                     \
        for (int j = (J0_); j <= (J1_); ++j) {                                \
            const int sl__ = ((TM_) + j + 1) % 11;                            \
            float wy__ = gs[10 - j];                                          \
            acc[0][sl__] = fmaf(wy__, u1__,  acc[0][sl__]);                   \
            acc[1][sl__] = fmaf(wy__, u2__,  acc[1][sl__]);                   \
            acc[2][sl__] = fmaf(wy__, ss__,  acc[2][sl__]);                   \
            acc[3][sl__] = fmaf(wy__, a12__, acc[3][sl__]);                   \
        }                                                                     \
    }                                                                         \
    *(float4*)(p_wr + (((T_) + 2) & 3) * RSLOT) = h1;  /* row T+2 */          \
    if (STORE_) {                                                             \
        const int es__ = ((TM_) + 1) % 11;                                    \
        float* wp__ = fb + (size_t)(y0 + T__ - 10) * FROW;                    \
        float2 lo__, hi__;                                                    \
        lo__.x = acc[0][es__]; lo__.y = acc[1][es__];                         \
        hi__.x = acc[2][es__]; hi__.y = acc[3][es__];                         \
        *(float2*)(wp__)     = lo__;                                          \
        *(float2*)(wp__ + 2) = hi__;                                          \
        acc[0][es__] = 0.f; acc[1][es__] = 0.f;                               \
        acc[2][es__] = 0.f; acc[3][es__] = 0.f;                               \
    }                                                                         \
    h1 = h2; h2 = Rn__;                                                       \
} while (0)

__global__ __launch_bounds__(128, 2)
void ssimA(const float* __restrict__ img1, const float* __restrict__ img2,
           float* __restrict__ fields) {
    __shared__ __align__(16) float ring[2 * WRING];   // 10 KiB (2 waves)
    float gs[11]; make_g_s(gs);
    const int x = threadIdx.x;                 // 0..127 (output column)
    const int w = x >> 6, l = x & 63;          // wave, lane
    const int b = blockIdx.x;
    const int yc = b & 7, z = (b >> 3) & 127, n = b >> 10;
    const int y0 = yc * 16;
    // lanes 0-31 stage the img1 row (float4 each), lanes 32-63 the img2 row
    const float* src = (l < 32 ? img1 : img2)
                     + (size_t)n * S + (size_t)z * SLICE + 4 * (l & 31);
    float* fb = fields + (size_t)(n * 128 + z) * FSL + 4 * x;

    // per-parity 12-tap weights over the aligned window [e, e+11],
    // e = (x-5)&~1, p = (x-5)&1; tap k has weight g[k-p] (0 outside 0..10).
    const int p = (x - 5) & 1;
    const int e = (x - 5) - p;                 // even, in [-6, 122]
    float w12[12];
#pragma unroll
    for (int k = 0; k < 12; ++k) {
        float we = (k <= 10) ? gs[k] : 0.f;            // p == 0
        float wo = (k >= 1) ? gs[k - 1] : 0.f;         // p == 1
        w12[k] = p ? wo : we;
    }

    float* wring = ring + w * WRING;           // private per-wave ring
    float* p_rd = wring + (8 + e);             // aligned window base (8B)
    float* p_wr = wring + ((l < 32) ? 0 : RB) + 8 + 4 * (l & 31);

    // zero whole ring once: pads stay zero forever (x-boundary = free)
    for (int i = l; i < WRING; i += 64) wring[i] = 0.f;

    float acc[4][11];
#pragma unroll
    for (int f = 0; f < 4; ++f)
#pragma unroll
        for (int s2 = 0; s2 < 11; ++s2) acc[f][s2] = 0.f;

    // prologue: slots 0,1 <- rows for steps 0,1; h1,h2 <- rows for steps 2,3
    float4 h1, h2;
    {
        int r0 = min(max(y0 - 5, 0), 127);
        int r1 = min(max(y0 - 4, 0), 127);
        int r2 = min(max(y0 - 3, 0), 127);
        int r3 = min(max(y0 - 2, 0), 127);
        float4 R0 = *(const float4*)(src + (size_t)r0 * 128);
        float4 R1 = *(const float4*)(src + (size_t)r1 * 128);
        h1        = *(const float4*)(src + (size_t)r2 * 128);
        h2        = *(const float4*)(src + (size_t)r3 * 128);
        *(float4*)(p_wr)         = R0;         // slot 0
        *(float4*)(p_wr + RSLOT) = R1;         // slot 1
    }

    // head: t = 0..9 (partial y-window, row may be < 0; no stores)
#pragma unroll
    for (int t = 0; t < 10; ++t)
        STEPA(t, t, 10 - t, 10, false, (y0 + t - 5 >= 0));
    // mid: t = 10..15 -- full window, store every step
#pragma unroll
    for (int t = 10; t < 16; ++t)
        STEPA(t, t % 11, 0, 10, true, true);
    // drain: t = 16..25 (tail taps; row may be > 127 only at yc=7; store)
#pragma unroll
    for (int t = 16; t < 26; ++t)
        STEPA(t, t % 11, 0, 25 - t, true, (y0 + t - 5 < 128));
}

// ---------------- Kernel B: z-conv + map + reduce, walk z ----------------
// grid: 4n * 64y2 * 4zc = 1024 blocks of 256 threads (4 waves) -- R13's
// best-total block shape, (256,1) = VGPR uncapped (~85 live, no spill).
// Thread owns (x = tid&127, y = 2*y2 + (tid>>7)); walks 32 z outputs.
// Batches reversed (freshest A output first -> L3 hits). Depth-6 float4
// named-register pipeline; x-major layout: ONE dwordx4 load per step.
#define STEPB(T_, TM_, J0_, J1_, STORE_, OKC_) do {                           \
    const int T__ = (T_);                                                     \
    int sp__ = T__ + 6; if (sp__ > 41) sp__ = 41;                             \
    size_t off__ = (size_t)min(max(z0 + sp__ - 5, 0), 127) * FSL;             \
    float4 N__ = *(const float4*)(base + off__);                              \
    if (OKC_) {                                                               \
        _Pragma("unroll")                                                     \
        for (int j = (J0_); j <= (J1_); ++j) {                                \
            const int sl__ = ((TM_) + j + 1) % 11;                            \
            float wz__ = gs[10 - j];                                          \
            acc[0][sl__] = fmaf(wz__, P0_.x, acc[0][sl__]);                   \
            acc[1][sl__] = fmaf(wz__, P0_.y, acc[1][sl__]);                   \
            acc[2][sl__] = fmaf(wz__, P0_.z, acc[2][sl__]);                   \
            acc[3][sl__] = fmaf(wz__, P0_.w, acc[3][sl__]);                   \
        }                                                                     \
    }                                                                         \
    if (STORE_) {                                                             \
        const int es__ = ((TM_) + 1) % 11;                                    \
        float m1__ = acc[0][es__], m2__ = acc[1][es__];                       \
        float ps__ = acc[2][es__], p12__ = acc[3][es__];                      \
        float m1s__ = m1__ * m1__, m2s__ = m2__ * m2__, m12__ = m1__ * m2__;  \
        float v12__ = ps__ - m1s__ - m2s__;     /* sigma1^2 + sigma2^2 */     \
        float cv__  = p12__ - m12__;            /* sigma12 */                 \
        float num__ = (2.f * m12__ + C1_) * (2.f * cv__ + C2_);               \
        float den__ = (m1s__ + m2s__ + C1_) * (v12__ + C2_);                  \
        sum += num__ / den__;                                                 \
        _Pragma("unroll")                                                     \
        for (int f = 0; f < 4; ++f) acc[f][es__] = 0.f;                       \
    }                                                                         \
    P0_ = P1_; P1_ = P2_; P2_ = P3_; P3_ = P4_; P4_ = P5_; P5_ = N__;         \
} while (0)

__global__ __launch_bounds__(256, 1)
void ssimB(const float* __restrict__ fields, float* __restrict__ partials) {
    float gs[11]; make_g_s(gs);
    const int tid = threadIdx.x;
    const int x = tid & 127, yr = tid >> 7;
    const int b = blockIdx.x;
    const int zc = b & 3, y2 = (b >> 2) & 63;
    const int n = 3 - (b >> 8);                 // reverse batches (L3 hits)
    const int y = y2 * 2 + yr;
    const int z0 = zc * 32;
    const float* base = fields + (size_t)n * 128 * FSL
                      + (size_t)y * FROW + 4 * x;

    float acc[4][11];
#pragma unroll
    for (int f = 0; f < 4; ++f)
#pragma unroll
        for (int s2 = 0; s2 < 11; ++s2) acc[f][s2] = 0.f;

    float sum = 0.f;

    // depth-6 prologue: slices for steps 0..5 (z0-5 .. z0)
    float4 P0_, P1_, P2_, P3_, P4_, P5_;
    {
        P0_ = *(const float4*)(base + (size_t)min(max(z0 - 5, 0), 127) * FSL);
        P1_ = *(const float4*)(base + (size_t)min(max(z0 - 4, 0), 127) * FSL);
        P2_ = *(const float4*)(base + (size_t)min(max(z0 - 3, 0), 127) * FSL);
        P3_ = *(const float4*)(base + (size_t)min(max(z0 - 2, 0), 127) * FSL);
        P4_ = *(const float4*)(base + (size_t)min(max(z0 - 1, 0), 127) * FSL);
        P5_ = *(const float4*)(base + (size_t)min(max(z0 - 0, 0), 127) * FSL);
    }

    // head: t = 0..9
#pragma unroll
    for (int t = 0; t < 10; ++t)
        STEPB(t, t, 10 - t, 10, false, (z0 + t - 5 >= 0));
    // steady: t = 10..31 -- branch-free
#pragma unroll 1
    for (int blk = 0; blk < 2; ++blk) {
#pragma unroll
        for (int tt = 0; tt < 11; ++tt)
            STEPB(10 + blk * 11 + tt, (10 + tt) % 11, 0, 10, true, true);
    }
    // drain: t = 32..41
#pragma unroll
    for (int t = 32; t < 42; ++t)
        STEPB(t, t % 11, 0, 41 - t, true, (z0 + t - 5 < 128));

    // 4-wave reduce
#pragma unroll
    for (int o = 32; o > 0; o >>= 1) sum += __shfl_down(sum, o, 64);
    __shared__ float ws4[4];
    if ((tid & 63) == 0) ws4[tid >> 6] = sum;
    __syncthreads();
    if (tid == 0) partials[blockIdx.x] = ws4[0] + ws4[1] + ws4[2] + ws4[3];
}

// ---------------- final reduce ----------------
__global__ void ssim_final(const float* __restrict__ partial, int n,
                           float* __restrict__ out, double inv_count) {
    int tid = threadIdx.x;
    double s = 0.0;
    for (int i = tid; i < n; i += 256) s += (double)partial[i];
#pragma unroll
    for (int o = 32; o > 0; o >>= 1) s += __shfl_down(s, o, 64);
    __shared__ double wsum[4];
    int lane = tid & 63, wid = tid >> 6;
    if (lane == 0) wsum[wid] = s;
    __syncthreads();
    if (tid == 0)
        out[0] = (float)((wsum[0] + wsum[1] + wsum[2] + wsum[3]) * inv_count);
}

extern "C" void kernel_launch(void* const* d_in, const int* in_sizes, int n_in,
                              void* d_out, int out_size, void* d_ws, size_t ws_size,
                              hipStream_t stream) {
    const float* img1 = (const float*)d_in[0];
    const float* img2 = (const float*)d_in[1];
    float* out = (float*)d_out;

    float* fields   = (float*)d_ws;                    // 16*S floats (134 MB)
    float* partials = fields + 16 * (size_t)S;         // 1024 floats

    ssimA<<<4096, 128, 0, stream>>>(img1, img2, fields);
    ssimB<<<1024, 256, 0, stream>>>(fields, partials);
    ssim_final<<<1, 256, 0, stream>>>(partials, 1024, out,
                                      1.0 / ((double)S * 4));
}

// Round 15
// 171.042 us; speedup vs baseline: 1.0583x; 1.0449x over previous
//
#include <hip/hip_runtime.h>

// SSIM3D, (4,1,128,128,128) fp32, separable 11-tap Gaussian, scalar mean out.
//
// R21: 4-WAVE A-BLOCKS (SPI launch-rate experiment) + proven-best pieces.
// R20 post-mortem: packed A-stores spill at the 128 cap (float2 == float4,
// WRITE 143360) -> A's optimum is R17's [f][x] layout + 4 coalesced scalar
// stores (71us, WRITE 131072, VGPR 112). Occupancy has been ~0.4x the
// resource cap in EVERY config (VGPR64->41%, VGPR104-128->15-17%):
// consistent with a workgroup-launch-rate (SPI) steady state. A's waves are
// fully independent (per-wave rings) -> pack 4 waves (2 z/yc units) per
// 256-thread block, grid 2048, (256,1) (cap 128 worst-case >= 112 demand).
// B: R13's best-shape (256-thr grid-1024) + 4-field scalar loads + depth-6.
// Invariants: A WRITE_SIZE == 131072 KB, VGPR <= 128, absmax 0.
// Decision: A ~71us + occ ~17% -> SPI theory dead -> accept ~165 or fuse.

#define SLICE (128*128)        // 16384
#define S  (128*SLICE)         // 2097152 per field per batch
#define ZROW 512               // floats per y-row: [4 fields][128 x]
#define ZSL  65536             // floats per z-slice (128 y * ZROW)
#define C1_ 0.0001f
#define C2_ 0.0009f

__device__ __forceinline__ void make_g_s(float* gs) {
    float g[11]; float s = 0.f;
#pragma unroll
    for (int i = 0; i < 11; ++i) {
        float d = (float)(i - 5);
        g[i] = __expf(-d * d / 4.5f);
        s += g[i];
    }
    float inv = 1.f / s;
#pragma unroll
    for (int i = 0; i < 11; ++i)
        gs[i] = __int_as_float(__builtin_amdgcn_readfirstlane(
                    __float_as_int(g[i] * inv)));
}

// ---------------- Kernel A: x-conv + y-conv, walk y ----------------
// grid: 2048 blocks of 256 threads = 4 independent waves. Wave pair
// p = w>>1 owns unit idx = blockIdx.x*2 + p (decoded n, z, yc); within the
// pair, wave w&1 owns x-half (x = (w&1)*64 + lane). Each wave stages the
// FULL row pair into its private LDS ring (lanes 0-31 img1, 32-63 img2).
// Thread walks 16 y outputs (26 input rows, fully unrolled).
// Ring: 4 slots x (img1 row | img2 row), rows padded to 160 floats (data at
// dwords [8..135], zeros outside): maskless 11-tap. Pipeline: global load
// row(t+4) at t; LDS-write row(t+2) at t; read slot t&3 (written t-2).
// Output: {conv a, conv b, conv(a^2+b^2), conv ab} at [f][x]-interleaved
// row, 4 coalesced scalar stores (proven no-spill form, R17).
#define RB    160              // dwords per padded row
#define RSLOT (2*RB)           // 320 dwords per ring slot
#define WRING (4*RSLOT)        // 1280 dwords per wave ring (4 slots) = 5 KiB

#define STEPA(T_, TM_, J0_, J1_, STORE_, OKC_) do {                           \
    const int T__ = (T_);                                                     \
    int sp__ = T__ + 4; if (sp__ > 25) sp__ = 25;                             \
    int rowc__ = min(max(y0 + sp__ - 5, 0), 127);                             \
    float4 Rn__ = *(const float4*)(src + (size_t)rowc__ * 128);               \
    if (OKC_) {                                                               \
        const float* rp__ = p_rd + ((T_) & 3) * RSLOT;                        \
        float u1__ = 0.f, u2__ = 0.f, ss__ = 0.f, a12__ = 0.f;                \
        _Pragma("unroll")                                                     \
        for (int j = 0; j < 6; ++j) {                                         \
            float2 va__ = *(const float2*)(rp__ + 2 * j);                     \
            float2 vb__ = *(const float2*)(rp__ + RB + 2 * j);                \
            {                                                                 \
                float wj__ = w12[2 * j];                                      \
                float ta__ = wj__ * va__.x, tb__ = wj__ * vb__.x;             \
                u1__ += ta__; u2__ += tb__;                                   \
                ss__  = fmaf(ta__, va__.x, ss__);                             \
                ss__  = fmaf(tb__, vb__.x, ss__);                             \
                a12__ = fmaf(ta__, vb__.x, a12__);                            \
            }                                                                 \
            {                                                                 \
                float wj__ = w12[2 * j + 1];                                  \
                float ta__ = wj__ * va__.y, tb__ = wj__ * vb__.y;             \
                u1__ += ta__; u2__ += tb__;                                   \
                ss__  = fmaf(ta__, va__.y, ss__);                             \
                ss__  = fmaf(tb__, vb__.y, ss__);                             \
                a12__ = fmaf(ta__, vb__.y, a12__);                            \
            }                                                                 \
        }                                                                     \
        _Pragma("unroll")                                                     \
        for (int j = (J0_); j <= (J1_); ++j) {                                \
            const int sl__ = ((TM_) + j + 1) % 11;                            \
            float wy__ = gs[10 - j];                                          \
            acc[0][sl__] = fmaf(wy__, u1__,  acc[0][sl__]);                   \
            acc[1][sl__] = fmaf(wy__, u2__,  acc[1][sl__]);                   \
            acc[2][sl__] = fmaf(wy__, ss__,  acc[2][sl__]);                   \
            acc[3][sl__] = fmaf(wy__, a12__, acc[3][sl__]);                   \
        }                                                                     \
    }                                                                         \
    *(float4*)(p_wr + (((T_) + 2) & 3) * RSLOT) = h1;  /* row T+2 */          \
    if (STORE_) {                                                             \
        size_t wo__ = (size_t)(y0 + T__ - 10) * ZROW;                         \
        const int es__ = ((TM_) + 1) % 11;                                    \
        _Pragma("unroll")                                                     \
        for (int f = 0; f < 4; ++f) {                                         \
            fb[wo__ + f * 128] = acc[f][es__];                                \
            acc[f][es__] = 0.f;                                               \
        }                                                                     \
    }                                                                         \
    h1 = h2; h2 = Rn__;                                                       \
} while (0)

__global__ __launch_bounds__(256, 1)
void ssimA(const float* __restrict__ img1, const float* __restrict__ img2,
           float* __restrict__ fields) {
    __shared__ __align__(16) float ring[4 * WRING];   // 20 KiB (4 waves)
    float gs[11]; make_g_s(gs);
    const int tid = threadIdx.x;
    const int w = tid >> 6, l = tid & 63;      // wave 0..3, lane 0..63
    const int idx = blockIdx.x * 2 + (w >> 1); // work unit 0..4095
    const int x = ((w & 1) << 6) + l;          // output column 0..127
    const int yc = idx & 7, z = (idx >> 3) & 127, n = idx >> 10;
    const int y0 = yc * 16;
    // lanes 0-31 stage the img1 row (float4 each), lanes 32-63 the img2 row
    const float* src = (l < 32 ? img1 : img2)
                     + (size_t)n * S + (size_t)z * SLICE + 4 * (l & 31);
    float* fb = fields + (size_t)(n * 128 + z) * ZSL + x;

    // per-parity 12-tap weights over the aligned window [e, e+11],
    // e = (x-5)&~1, p = (x-5)&1; tap k has weight g[k-p] (0 outside 0..10).
    const int p = (x - 5) & 1;
    const int e = (x - 5) - p;                 // even, in [-6, 122]
    float w12[12];
#pragma unroll
    for (int k = 0; k < 12; ++k) {
        float we = (k <= 10) ? gs[k] : 0.f;            // p == 0
        float wo = (k >= 1) ? gs[k - 1] : 0.f;         // p == 1
        w12[k] = p ? wo : we;
    }

    float* wring = ring + w * WRING;           // private per-wave ring
    float* p_rd = wring + (8 + e);             // aligned window base (8B)
    float* p_wr = wring + ((l < 32) ? 0 : RB) + 8 + 4 * (l & 31);

    // zero whole ring once: pads stay zero forever (x-boundary = free)
    for (int i = l; i < WRING; i += 64) wring[i] = 0.f;

    float acc[4][11];
#pragma unroll
    for (int f = 0; f < 4; ++f)
#pragma unroll
        for (int s2 = 0; s2 < 11; ++s2) acc[f][s2] = 0.f;

    // prologue: slots 0,1 <- rows for steps 0,1; h1,h2 <- rows for steps 2,3
    float4 h1, h2;
    {
        int r0 = min(max(y0 - 5, 0), 127);
        int r1 = min(max(y0 - 4, 0), 127);
        int r2 = min(max(y0 - 3, 0), 127);
        int r3 = min(max(y0 - 2, 0), 127);
        float4 R0 = *(const float4*)(src + (size_t)r0 * 128);
        float4 R1 = *(const float4*)(src + (size_t)r1 * 128);
        h1        = *(const float4*)(src + (size_t)r2 * 128);
        h2        = *(const float4*)(src + (size_t)r3 * 128);
        *(float4*)(p_wr)         = R0;         // slot 0
        *(float4*)(p_wr + RSLOT) = R1;         // slot 1
    }

    // head: t = 0..9 (partial y-window, row may be < 0; no stores)
#pragma unroll
    for (int t = 0; t < 10; ++t)
        STEPA(t, t, 10 - t, 10, false, (y0 + t - 5 >= 0));
    // mid: t = 10..15 -- full window, store every step
#pragma unroll
    for (int t = 10; t < 16; ++t)
        STEPA(t, t % 11, 0, 10, true, true);
    // drain: t = 16..25 (tail taps; row may be > 127 only at yc=7; store)
#pragma unroll
    for (int t = 16; t < 26; ++t)
        STEPA(t, t % 11, 0, 25 - t, true, (y0 + t - 5 < 128));
}

// ---------------- Kernel B: z-conv + map + reduce, walk z ----------------
// grid: 4n * 64y2 * 4zc = 1024 blocks of 256 threads (4 waves) -- R13's
// best-total shape, (256,1) uncapped (~85 live, no spill).
// Thread owns (x = tid&127, y = 2*y2 + (tid>>7)); walks 32 z outputs.
// Batches reversed (freshest A output first -> L3 hits). Depth-6 prefetch
// (P0..P5, static-indexed arrays); [f][x] layout: 4 coalesced scalar loads.
#define STEPB(T_, TM_, J0_, J1_, STORE_, OKC_) do {                           \
    const int T__ = (T_);                                                     \
    int sp__ = T__ + 6; if (sp__ > 41) sp__ = 41;                             \
    size_t off__ = (size_t)min(max(z0 + sp__ - 5, 0), 127) * ZSL;             \
    float N0__ = base[off__];                                                 \
    float N1__ = base[off__ + 128];                                           \
    float N2__ = base[off__ + 256];                                           \
    float N3__ = base[off__ + 384];                                           \
    if (OKC_) {                                                               \
        _Pragma("unroll")                                                     \
        for (int j = (J0_); j <= (J1_); ++j) {                                \
            const int sl__ = ((TM_) + j + 1) % 11;                            \
            float wz__ = gs[10 - j];                                          \
            acc[0][sl__] = fmaf(wz__, P0[0], acc[0][sl__]);                   \
            acc[1][sl__] = fmaf(wz__, P0[1], acc[1][sl__]);                   \
            acc[2][sl__] = fmaf(wz__, P0[2], acc[2][sl__]);                   \
            acc[3][sl__] = fmaf(wz__, P0[3], acc[3][sl__]);                   \
        }                                                                     \
    }                                                                         \
    if (STORE_) {                                                             \
        const int es__ = ((TM_) + 1) % 11;                                    \
        float m1__ = acc[0][es__], m2__ = acc[1][es__];                       \
        float ps__ = acc[2][es__], p12__ = acc[3][es__];                      \
        float m1s__ = m1__ * m1__, m2s__ = m2__ * m2__, m12__ = m1__ * m2__;  \
        float v12__ = ps__ - m1s__ - m2s__;     /* sigma1^2 + sigma2^2 */     \
        float cv__  = p12__ - m12__;            /* sigma12 */                 \
        float num__ = (2.f * m12__ + C1_) * (2.f * cv__ + C2_);               \
        float den__ = (m1s__ + m2s__ + C1_) * (v12__ + C2_);                  \
        sum += num__ / den__;                                                 \
        _Pragma("unroll")                                                     \
        for (int f = 0; f < 4; ++f) acc[f][es__] = 0.f;                       \
    }                                                                         \
    _Pragma("unroll")                                                         \
    for (int f = 0; f < 4; ++f) {                                             \
        P0[f] = P1[f]; P1[f] = P2[f]; P2[f] = P3[f];                          \
        P3[f] = P4[f]; P4[f] = P5[f];                                         \
    }                                                                         \
    P5[0] = N0__; P5[1] = N1__; P5[2] = N2__; P5[3] = N3__;                   \
} while (0)

__global__ __launch_bounds__(256, 1)
void ssimB(const float* __restrict__ fields, float* __restrict__ partials) {
    float gs[11]; make_g_s(gs);
    const int tid = threadIdx.x;
    const int x = tid & 127, yr = tid >> 7;
    const int b = blockIdx.x;
    const int zc = b & 3, y2 = (b >> 2) & 63;
    const int n = 3 - (b >> 8);                 // reverse batches (L3 hits)
    const int y = y2 * 2 + yr;
    const int z0 = zc * 32;
    const float* base = fields + (size_t)n * 128 * ZSL
                      + (size_t)y * ZROW + x;

    float acc[4][11];
#pragma unroll
    for (int f = 0; f < 4; ++f)
#pragma unroll
        for (int s2 = 0; s2 < 11; ++s2) acc[f][s2] = 0.f;

    float sum = 0.f;

    // depth-6 prologue: slices for steps 0..5 (z0-5 .. z0)
    float P0[4], P1[4], P2[4], P3[4], P4[4], P5[4];
    {
        size_t o0 = (size_t)min(max(z0 - 5, 0), 127) * ZSL;
        size_t o1 = (size_t)min(max(z0 - 4, 0), 127) * ZSL;
        size_t o2 = (size_t)min(max(z0 - 3, 0), 127) * ZSL;
        size_t o3 = (size_t)min(max(z0 - 2, 0), 127) * ZSL;
        size_t o4 = (size_t)min(max(z0 - 1, 0), 127) * ZSL;
        size_t o5 = (size_t)min(max(z0 - 0, 0), 127) * ZSL;
#pragma unroll
        for (int f = 0; f < 4; ++f) {
            P0[f] = base[o0 + f * 128];
            P1[f] = base[o1 + f * 128];
            P2[f] = base[o2 + f * 128];
            P3[f] = base[o3 + f * 128];
            P4[f] = base[o4 + f * 128];
            P5[f] = base[o5 + f * 128];
        }
    }

    // head: t = 0..9
#pragma unroll
    for (int t = 0; t < 10; ++t)
        STEPB(t, t, 10 - t, 10, false, (z0 + t - 5 >= 0));
    // steady: t = 10..31 -- branch-free
#pragma unroll 1
    for (int blk = 0; blk < 2; ++blk) {
#pragma unroll
        for (int tt = 0; tt < 11; ++tt)
            STEPB(10 + blk * 11 + tt, (10 + tt) % 11, 0, 10, true, true);
    }
    // drain: t = 32..41
#pragma unroll
    for (int t = 32; t < 42; ++t)
        STEPB(t, t % 11, 0, 41 - t, true, (z0 + t - 5 < 128));

    // 4-wave reduce
#pragma unroll
    for (int o = 32; o > 0; o >>= 1) sum += __shfl_down(sum, o, 64);
    __shared__ float ws4[4];
    if ((tid & 63) == 0) ws4[tid >> 6] = sum;
    __syncthreads();
    if (tid == 0) partials[blockIdx.x] = ws4[0] + ws4[1] + ws4[2] + ws4[3];
}

// ---------------- final reduce ----------------
__global__ void ssim_final(const float* __restrict__ partial, int n,
                           float* __restrict__ out, double inv_count) {
    int tid = threadIdx.x;
    double s = 0.0;
    for (int i = tid; i < n; i += 256) s += (double)partial[i];
#pragma unroll
    for (int o = 32; o > 0; o >>= 1) s += __shfl_down(s, o, 64);
    __shared__ double wsum[4];
    int lane = tid & 63, wid = tid >> 6;
    if (lane == 0) wsum[wid] = s;
    __syncthreads();
    if (tid == 0)
        out[0] = (float)((wsum[0] + wsum[1] + wsum[2] + wsum[3]) * inv_count);
}

extern "C" void kernel_launch(void* const* d_in, const int* in_sizes, int n_in,
                              void* d_out, int out_size, void* d_ws, size_t ws_size,
                              hipStream_t stream) {
    const float* img1 = (const float*)d_in[0];
    const float* img2 = (const float*)d_in[1];
    float* out = (float*)d_out;

    float* fields   = (float*)d_ws;                    // 16*S floats (134 MB)
    float* partials = fields + 16 * (size_t)S;         // 1024 floats

    ssimA<<<2048, 256, 0, stream>>>(img1, img2, fields);
    ssimB<<<1024, 256, 0, stream>>>(fields, partials);
    ssim_final<<<1, 256, 0, stream>>>(partials, 1024, out,
                                      1.0 / ((double)S * 4));
}

// Round 16
// 170.919 us; speedup vs baseline: 1.0591x; 1.0007x over previous
//
#include <hip/hip_runtime.h>

// SSIM3D, (4,1,128,128,128) fp32, separable 11-tap Gaussian, scalar mean out.
//
// R22: Z-INNER INTERMEDIATE LAYOUT [n][y][z][f][x] (B-stream fix).
// R21 post-mortem: SPI theory dead (4-wave A blocks -> occ still 17%).
// A floor ~71us accepted (6 variants, 70-76us, WRITE 131072 no-spill).
// Ledger: B ~95us at 1.4 TB/s (22% HBM) -> latency-bound. Mechanism: B's
// z-walk strides 256KB/step (z-slice pitch) -> zero DRAM/prefetch locality,
// every step pays full L3 latency on ~1.4 waves/SIMD TLP. With z innermost,
// B's stream is SEQUENTIAL (2KB/step, 86KB contiguous per y-row); A's
// stores become 16 scattered 2KB rows (fire-and-forget, bytes unchanged).
// ONLY index arithmetic changed from R21 (both kernels' structure proven).
// Invariants: A WRITE_SIZE == 131072 KB, VGPR <= 128, absmax 0.
// Decision: total >= 165 -> plateau structural -> fusion-or-stop.

#define SLICE (128*128)        // 16384
#define S  (128*SLICE)         // 2097152 per field per batch
#define FR  512                // floats per (y,z) field-row: [4 f][128 x]
#define C1_ 0.0001f
#define C2_ 0.0009f

__device__ __forceinline__ void make_g_s(float* gs) {
    float g[11]; float s = 0.f;
#pragma unroll
    for (int i = 0; i < 11; ++i) {
        float d = (float)(i - 5);
        g[i] = __expf(-d * d / 4.5f);
        s += g[i];
    }
    float inv = 1.f / s;
#pragma unroll
    for (int i = 0; i < 11; ++i)
        gs[i] = __int_as_float(__builtin_amdgcn_readfirstlane(
                    __float_as_int(g[i] * inv)));
}

// ---------------- Kernel A: x-conv + y-conv, walk y ----------------
// grid: 2048 blocks of 256 threads = 4 independent waves. Wave pair
// p = w>>1 owns unit idx = blockIdx.x*2 + p (decoded n, z, yc); within the
// pair, wave w&1 owns x-half (x = (w&1)*64 + lane). Each wave stages the
// FULL row pair into its private LDS ring (lanes 0-31 img1, 32-63 img2).
// Thread walks 16 y outputs (26 input rows, fully unrolled).
// Ring: 4 slots x (img1 row | img2 row), rows padded to 160 floats (data at
// dwords [8..135], zeros outside): maskless 11-tap. Pipeline: global load
// row(t+4) at t; LDS-write row(t+2) at t; read slot t&3 (written t-2).
// Output row (y,z): {conv a, conv b, conv(a^2+b^2), conv ab} at
// fields[((n*128+y)*128+z)*512 + f*128 + x], 4 coalesced scalar stores.
#define RB    160              // dwords per padded row
#define RSLOT (2*RB)           // 320 dwords per ring slot
#define WRING (4*RSLOT)        // 1280 dwords per wave ring (4 slots) = 5 KiB

#define STEPA(T_, TM_, J0_, J1_, STORE_, OKC_) do {                           \
    const int T__ = (T_);                                                     \
    int sp__ = T__ + 4; if (sp__ > 25) sp__ = 25;                             \
    int rowc__ = min(max(y0 + sp__ - 5, 0), 127);                             \
    float4 Rn__ = *(const float4*)(src + (size_t)rowc__ * 128);               \
    if (OKC_) {                                                               \
        const float* rp__ = p_rd + ((T_) & 3) * RSLOT;                        \
        float u1__ = 0.f, u2__ = 0.f, ss__ = 0.f, a12__ = 0.f;                \
        _Pragma("unroll")                                                     \
        for (int j = 0; j < 6; ++j) {                                         \
            float2 va__ = *(const float2*)(rp__ + 2 * j);                     \
            float2 vb__ = *(const float2*)(rp__ + RB + 2 * j);                \
            {                                                                 \
                float wj__ = w12[2 * j];                                      \
                float ta__ = wj__ * va__.x, tb__ = wj__ * vb__.x;             \
                u1__ += ta__; u2__ += tb__;                                   \
                ss__  = fmaf(ta__, va__.x, ss__);                             \
                ss__  = fmaf(tb__, vb__.x, ss__);                             \
                a12__ = fmaf(ta__, vb__.x, a12__);                            \
            }                                                                 \
            {                                                                 \
                float wj__ = w12[2 * j + 1];                                  \
                float ta__ = wj__ * va__.y, tb__ = wj__ * vb__.y;             \
                u1__ += ta__; u2__ += tb__;                                   \
                ss__  = fmaf(ta__, va__.y, ss__);                             \
                ss__  = fmaf(tb__, vb__.y, ss__);                             \
                a12__ = fmaf(ta__, vb__.y, a12__);                            \
            }                                                                 \
        }                                                                     \
        _Pragma("unroll")                                                     \
        for (int j = (J0_); j <= (J1_); ++j) {                                \
            const int sl__ = ((TM_) + j + 1) % 11;                            \
            float wy__ = gs[10 - j];                                          \
            acc[0][sl__] = fmaf(wy__, u1__,  acc[0][sl__]);                   \
            acc[1][sl__] = fmaf(wy__, u2__,  acc[1][sl__]);                   \
            acc[2][sl__] = fmaf(wy__, ss__,  acc[2][sl__]);                   \
            acc[3][sl__] = fmaf(wy__, a12__, acc[3][sl__]);                   \
        }                                                                     \
    }                                                                         \
    *(float4*)(p_wr + (((T_) + 2) & 3) * RSLOT) = h1;  /* row T+2 */          \
    if (STORE_) {                                                             \
        size_t wo__ = (size_t)(y0 + T__ - 10) * (128 * FR);                   \
        const int es__ = ((TM_) + 1) % 11;                                    \
        _Pragma("unroll")                                                     \
        for (int f = 0; f < 4; ++f) {                                         \
            fb[wo__ + f * 128] = acc[f][es__];                                \
            acc[f][es__] = 0.f;                                               \
        }                                                                     \
    }                                                                         \
    h1 = h2; h2 = Rn__;                                                       \
} while (0)

__global__ __launch_bounds__(256, 1)
void ssimA(const float* __restrict__ img1, const float* __restrict__ img2,
           float* __restrict__ fields) {
    __shared__ __align__(16) float ring[4 * WRING];   // 20 KiB (4 waves)
    float gs[11]; make_g_s(gs);
    const int tid = threadIdx.x;
    const int w = tid >> 6, l = tid & 63;      // wave 0..3, lane 0..63
    const int idx = blockIdx.x * 2 + (w >> 1); // work unit 0..4095
    const int x = ((w & 1) << 6) + l;          // output column 0..127
    const int yc = idx & 7, z = (idx >> 3) & 127, n = idx >> 10;
    const int y0 = yc * 16;
    // lanes 0-31 stage the img1 row (float4 each), lanes 32-63 the img2 row
    const float* src = (l < 32 ? img1 : img2)
                     + (size_t)n * S + (size_t)z * SLICE + 4 * (l & 31);
    // z-inner layout: element (n,y,z,f,x) at ((n*128+y)*128+z)*FR + f*128+x.
    // Per-thread base carries (n, z, x); y added per store step.
    float* fb = fields + ((size_t)n * 128 * 128 + z) * FR + x;

    // per-parity 12-tap weights over the aligned window [e, e+11],
    // e = (x-5)&~1, p = (x-5)&1; tap k has weight g[k-p] (0 outside 0..10).
    const int p = (x - 5) & 1;
    const int e = (x - 5) - p;                 // even, in [-6, 122]
    float w12[12];
#pragma unroll
    for (int k = 0; k < 12; ++k) {
        float we = (k <= 10) ? gs[k] : 0.f;            // p == 0
        float wo = (k >= 1) ? gs[k - 1] : 0.f;         // p == 1
        w12[k] = p ? wo : we;
    }

    float* wring = ring + w * WRING;           // private per-wave ring
    float* p_rd = wring + (8 + e);             // aligned window base (8B)
    float* p_wr = wring + ((l < 32) ? 0 : RB) + 8 + 4 * (l & 31);

    // zero whole ring once: pads stay zero forever (x-boundary = free)
    for (int i = l; i < WRING; i += 64) wring[i] = 0.f;

    float acc[4][11];
#pragma unroll
    for (int f = 0; f < 4; ++f)
#pragma unroll
        for (int s2 = 0; s2 < 11; ++s2) acc[f][s2] = 0.f;

    // prologue: slots 0,1 <- rows for steps 0,1; h1,h2 <- rows for steps 2,3
    float4 h1, h2;
    {
        int r0 = min(max(y0 - 5, 0), 127);
        int r1 = min(max(y0 - 4, 0), 127);
        int r2 = min(max(y0 - 3, 0), 127);
        int r3 = min(max(y0 - 2, 0), 127);
        float4 R0 = *(const float4*)(src + (size_t)r0 * 128);
        float4 R1 = *(const float4*)(src + (size_t)r1 * 128);
        h1        = *(const float4*)(src + (size_t)r2 * 128);
        h2        = *(const float4*)(src + (size_t)r3 * 128);
        *(float4*)(p_wr)         = R0;         // slot 0
        *(float4*)(p_wr + RSLOT) = R1;         // slot 1
    }

    // head: t = 0..9 (partial y-window, row may be < 0; no stores)
#pragma unroll
    for (int t = 0; t < 10; ++t)
        STEPA(t, t, 10 - t, 10, false, (y0 + t - 5 >= 0));
    // mid: t = 10..15 -- full window, store every step
#pragma unroll
    for (int t = 10; t < 16; ++t)
        STEPA(t, t % 11, 0, 10, true, true);
    // drain: t = 16..25 (tail taps; row may be > 127 only at yc=7; store)
#pragma unroll
    for (int t = 16; t < 26; ++t)
        STEPA(t, t % 11, 0, 25 - t, true, (y0 + t - 5 < 128));
}

// ---------------- Kernel B: z-conv + map + reduce, walk z ----------------
// grid: 4n * 64y2 * 4zc = 1024 blocks of 256 threads (4 waves).
// Thread owns (x = tid&127, y = 2*y2 + (tid>>7)); walks 32 z outputs.
// Z-INNER layout: each step advances exactly FR floats (2 KB) -- the whole
// pass is an 86 KB SEQUENTIAL stream per y-row (DRAM/prefetch friendly).
// Batches reversed (freshest A output first -> L3 hits). Depth-6 prefetch
// (P0..P5, static-indexed arrays); 4 coalesced scalar loads per step.
#define STEPB(T_, TM_, J0_, J1_, STORE_, OKC_) do {                           \
    const int T__ = (T_);                                                     \
    int sp__ = T__ + 6; if (sp__ > 41) sp__ = 41;                             \
    size_t off__ = (size_t)min(max(z0 + sp__ - 5, 0), 127) * FR;              \
    float N0__ = base[off__];                                                 \
    float N1__ = base[off__ + 128];                                           \
    float N2__ = base[off__ + 256];                                           \
    float N3__ = base[off__ + 384];                                           \
    if (OKC_) {                                                               \
        _Pragma("unroll")                                                     \
        for (int j = (J0_); j <= (J1_); ++j) {                                \
            const int sl__ = ((TM_) + j + 1) % 11;                            \
            float wz__ = gs[10 - j];                                          \
            acc[0][sl__] = fmaf(wz__, P0[0], acc[0][sl__]);                   \
            acc[1][sl__] = fmaf(wz__, P0[1], acc[1][sl__]);                   \
            acc[2][sl__] = fmaf(wz__, P0[2], acc[2][sl__]);                   \
            acc[3][sl__] = fmaf(wz__, P0[3], acc[3][sl__]);                   \
        }                                                                     \
    }                                                                         \
    if (STORE_) {                                                             \
        const int es__ = ((TM_) + 1) % 11;                                    \
        float m1__ = acc[0][es__], m2__ = acc[1][es__];                       \
        float ps__ = acc[2][es__], p12__ = acc[3][es__];                      \
        float m1s__ = m1__ * m1__, m2s__ = m2__ * m2__, m12__ = m1__ * m2__;  \
        float v12__ = ps__ - m1s__ - m2s__;     /* sigma1^2 + sigma2^2 */     \
        float cv__  = p12__ - m12__;            /* sigma12 */                 \
        float num__ = (2.f * m12__ + C1_) * (2.f * cv__ + C2_);               \
        float den__ = (m1s__ + m2s__ + C1_) * (v12__ + C2_);                  \
        sum += num__ / den__;                                                 \
        _Pragma("unroll")                                                     \
        for (int f = 0; f < 4; ++f) acc[f][es__] = 0.f;                       \
    }                                                                         \
    _Pragma("unroll")                                                         \
    for (int f = 0; f < 4; ++f) {                                             \
        P0[f] = P1[f]; P1[f] = P2[f]; P2[f] = P3[f];                          \
        P3[f] = P4[f]; P4[f] = P5[f];                                         \
    }                                                                         \
    P5[0] = N0__; P5[1] = N1__; P5[2] = N2__; P5[3] = N3__;                   \
} while (0)

__global__ __launch_bounds__(256, 1)
void ssimB(const float* __restrict__ fields, float* __restrict__ partials) {
    float gs[11]; make_g_s(gs);
    const int tid = threadIdx.x;
    const int x = tid & 127, yr = tid >> 7;
    const int b = blockIdx.x;
    const int zc = b & 3, y2 = (b >> 2) & 63;
    const int n = 3 - (b >> 8);                 // reverse batches (L3 hits)
    const int y = y2 * 2 + yr;
    const int z0 = zc * 32;
    const float* base = fields + ((size_t)n * 128 + y) * 128 * FR + x;

    float acc[4][11];
#pragma unroll
    for (int f = 0; f < 4; ++f)
#pragma unroll
        for (int s2 = 0; s2 < 11; ++s2) acc[f][s2] = 0.f;

    float sum = 0.f;

    // depth-6 prologue: slices for steps 0..5 (z0-5 .. z0)
    float P0[4], P1[4], P2[4], P3[4], P4[4], P5[4];
    {
        size_t o0 = (size_t)min(max(z0 - 5, 0), 127) * FR;
        size_t o1 = (size_t)min(max(z0 - 4, 0), 127) * FR;
        size_t o2 = (size_t)min(max(z0 - 3, 0), 127) * FR;
        size_t o3 = (size_t)min(max(z0 - 2, 0), 127) * FR;
        size_t o4 = (size_t)min(max(z0 - 1, 0), 127) * FR;
        size_t o5 = (size_t)min(max(z0 - 0, 0), 127) * FR;
#pragma unroll
        for (int f = 0; f < 4; ++f) {
            P0[f] = base[o0 + f * 128];
            P1[f] = base[o1 + f * 128];
            P2[f] = base[o2 + f * 128];
            P3[f] = base[o3 + f * 128];
            P4[f] = base[o4 + f * 128];
            P5[f] = base[o5 + f * 128];
        }
    }

    // head: t = 0..9
#pragma unroll
    for (int t = 0; t < 10; ++t)
        STEPB(t, t, 10 - t, 10, false, (z0 + t - 5 >= 0));
    // steady: t = 10..31 -- branch-free
#pragma unroll 1
    for (int blk = 0; blk < 2; ++blk) {
#pragma unroll
        for (int tt = 0; tt < 11; ++tt)
            STEPB(10 + blk * 11 + tt, (10 + tt) % 11, 0, 10, true, true);
    }
    // drain: t = 32..41
#pragma unroll
    for (int t = 32; t < 42; ++t)
        STEPB(t, t % 11, 0, 41 - t, true, (z0 + t - 5 < 128));

    // 4-wave reduce
#pragma unroll
    for (int o = 32; o > 0; o >>= 1) sum += __shfl_down(sum, o, 64);
    __shared__ float ws4[4];
    if ((tid & 63) == 0) ws4[tid >> 6] = sum;
    __syncthreads();
    if (tid == 0) partials[blockIdx.x] = ws4[0] + ws4[1] + ws4[2] + ws4[3];
}

// ---------------- final reduce ----------------
__global__ void ssim_final(const float* __restrict__ partial, int n,
                           float* __restrict__ out, double inv_count) {
    int tid = threadIdx.x;
    double s = 0.0;
    for (int i = tid; i < n; i += 256) s += (double)partial[i];
#pragma unroll
    for (int o = 32; o > 0; o >>= 1) s += __shfl_down(s, o, 64);
    __shared__ double wsum[4];
    int lane = tid & 63, wid = tid >> 6;
    if (lane == 0) wsum[wid] = s;
    __syncthreads();
    if (tid == 0)
        out[0] = (float)((wsum[0] + wsum[1] + wsum[2] + wsum[3]) * inv_count);
}

extern "C" void kernel_launch(void* const* d_in, const int* in_sizes, int n_in,
                              void* d_out, int out_size, void* d_ws, size_t ws_size,
                              hipStream_t stream) {
    const float* img1 = (const float*)d_in[0];
    const float* img2 = (const float*)d_in[1];
    float* out = (float*)d_out;

    float* fields   = (float*)d_ws;                    // 16*S floats (134 MB)
    float* partials = fields + 16 * (size_t)S;         // 1024 floats

    ssimA<<<2048, 256, 0, stream>>>(img1, img2, fields);
    ssimB<<<1024, 256, 0, stream>>>(fields, partials);
    ssim_final<<<1, 256, 0, stream>>>(partials, 1024, out,
                                      1.0 / ((double)S * 4));
}